// Round 10
// baseline (199.058 us; speedup 1.0000x reference)
//
#include <hip/hip_runtime.h>

#define BB 64
#define TT 4096
#define CC 51
#define DD 64
#define LN_EPS 1e-5f

typedef __attribute__((ext_vector_type(8))) short short8;
typedef __attribute__((ext_vector_type(4))) float f32x4;

union FragU { int i[4]; short8 s; };

// DPP control codes (verified R3-R5)
#define DPP_QP_1032   0xB1
#define DPP_QP_2301   0x4E
#define DPP_ROW_HMIRR 0x141
#define DPP_ROW_MIRR  0x140

__device__ __forceinline__ float dpp_add(float v, int tag) {
  int t;
  switch (tag) {
    case 0: t = __builtin_amdgcn_update_dpp(0, __float_as_int(v), DPP_QP_1032,   0xF, 0xF, true); break;
    case 1: t = __builtin_amdgcn_update_dpp(0, __float_as_int(v), DPP_QP_2301,   0xF, 0xF, true); break;
    case 2: t = __builtin_amdgcn_update_dpp(0, __float_as_int(v), DPP_ROW_HMIRR, 0xF, 0xF, true); break;
    default: t = __builtin_amdgcn_update_dpp(0, __float_as_int(v), DPP_ROW_MIRR, 0xF, 0xF, true); break;
  }
  return v + __int_as_float(t);
}
__device__ __forceinline__ float allsum16(float v) {
  v = dpp_add(v, 0); v = dpp_add(v, 1); v = dpp_add(v, 2); v = dpp_add(v, 3);
  return v;
}
__device__ __forceinline__ float allsum64(float v) {
  v = allsum16(v);
  v += __shfl_xor(v, 16, 64);
  v += __shfl_xor(v, 32, 64);
  return v;
}

// fp32 -> packed (bf16 hi | bf16 lo) dword; k=2c gets hi (low short), 2c+1 lo
__device__ __forceinline__ int pack_hl(float x) {
  const unsigned u = __float_as_uint(x);
  const unsigned h = u >> 16;
  const float hf = __uint_as_float(u & 0xFFFF0000u);
  const unsigned l = __float_as_uint(x - hf) >> 16;
  return (int)(h | (l << 16));
}

// ---- x prefetch for one 16-row chunk (13 VMEM loads + 1 tmask dword) ----
__device__ __forceinline__ void loadX(const float* __restrict__ x,
                                      const int* __restrict__ tmask,
                                      int rowCh, int q, int m16, int L,
                                      float (&xf)[4][4], int& tm) {
  const float* xr = x + (size_t)(rowCh + m16) * CC;
#pragma unroll
  for (int ks = 0; ks < 3; ++ks) {
    f32x4 v;
    __builtin_memcpy(&v, xr + ks * 16 + q * 4, 16);
    xf[ks][0] = v[0]; xf[ks][1] = v[1]; xf[ks][2] = v[2]; xf[ks][3] = v[3];
  }
  if (q == 0) {
    xf[3][0] = xr[48]; xf[3][1] = xr[49]; xf[3][2] = xr[50]; xf[3][3] = 0.0f;
  } else {
    xf[3][0] = 0.0f; xf[3][1] = 0.0f; xf[3][2] = 0.0f; xf[3][3] = 0.0f;
  }
  tm = tmask[rowCh + (L & 15)];
}

// ---- MFMA for one 16-row chunk: VMEM-free (B frags from LDS table) ----
__device__ __forceinline__ void compMFMA(const int (*tab)[4][64][4],
                                         const float (&xf)[4][4], int L,
                                         const float (&bias_)[4],
                                         f32x4 (&acc)[4]) {
#pragma unroll
  for (int nt = 0; nt < 4; ++nt) {
    acc[nt][0] = bias_[nt]; acc[nt][1] = bias_[nt];
    acc[nt][2] = bias_[nt]; acc[nt][3] = bias_[nt];
  }
#pragma unroll
  for (int ks = 0; ks < 4; ++ks) {
    FragU au;
#pragma unroll
    for (int j = 0; j < 4; ++j) au.i[j] = pack_hl(xf[ks][j]);
#pragma unroll
    for (int nt = 0; nt < 4; ++nt) {
      int hl[4];
      __builtin_memcpy(hl, &tab[ks][nt][L][0], 16);       // ds_read_b128
      FragU bmu, bcu;
#pragma unroll
      for (int j = 0; j < 4; ++j) {
        bmu.i[j] = (hl[j] & 0xFFFF) | (hl[j] << 16);      // (h, h)
        bcu.i[j] = (int)((unsigned)hl[j] >> 16);          // (l, 0)
      }
      acc[nt] = __builtin_amdgcn_mfma_f32_16x16x32_bf16(au.s, bmu.s, acc[nt], 0, 0, 0);
      acc[nt] = __builtin_amdgcn_mfma_f32_16x16x32_bf16(au.s, bcu.s, acc[nt], 0, 0, 0);
    }
  }
}

// ---- LN + wide NT store for one chunk ----
__device__ __forceinline__ void lnStore(const f32x4 (&acc)[4], int tmv,
                                        int q, int m16,
                                        const float (&cons_)[4],
                                        const float (&g_)[4], const float (&b_)[4],
                                        float* __restrict__ outCh) {
#pragma unroll
  for (int rg = 0; rg < 4; ++rg) {
    float su = 0.0f, sq = 0.0f;
#pragma unroll
    for (int nt = 0; nt < 4; ++nt) {
      const float v = acc[nt][rg];
      su += v;
      sq = fmaf(v, v, sq);
    }
    su = allsum16(su);
    sq = allsum16(sq);
    const float mu = su * (1.0f / 64.0f);
    const float vr = fmaf(-mu, mu, sq * (1.0f / 64.0f));
    const float rs = rsqrtf(vr + LN_EPS);
    const int rloc = q * 4 + rg;                 // 0..15 within chunk
    const int tm = __shfl(tmv, rloc, 64);
    f32x4 v4;
#pragma unroll
    for (int nt = 0; nt < 4; ++nt) {
      float val = fmaf((acc[nt][rg] - mu) * rs, g_[nt], b_[nt]);
      if (tm) val = cons_[nt];
      v4[nt] = val;
    }
    __builtin_nontemporal_store(v4, (f32x4*)(outCh + rloc * DD + m16 * 4));
  }
}

// ---- pipelined kernel: 64 rows/wave in 4 chunks, 3 x-buffers, LDS B-table.
// Loads of chunk k+1..k+2 overlap compute of chunk k; compute phase is
// VMEM-free so vmcnt waits touch only the owning chunk's loads. ----
__global__ __launch_bounds__(256, 4)
void ipmask_mfma12(const float* __restrict__ x, const float* __restrict__ W,
                   const float* __restrict__ Wm,
                   const float* __restrict__ gamma, const float* __restrict__ beta,
                   const int* __restrict__ tmask, const int* __restrict__ smask,
                   float* __restrict__ out) {
  const int t = threadIdx.x, L = t & 63, w = t >> 6;
  const int q = L >> 4, m16 = L & 15;
  const int gw = (blockIdx.x << 2) + w;              // 4096 waves
  const int b = gw >> 6;                             // 64 waves per b
  const int rowBase = (b << 12) + ((gw & 63) << 6);  // 64 rows per wave

  const int* smB = smask + b * CC;

  __shared__ int tabHL[4][4][64][4];   // [ks][nt][lane][j], 16 KB
  __shared__ float red[8][64];

  // ---- phase 0: issue preamble global loads (L1/L2-hot) FIRST ----
  float wraw[16];
  {
    const int nb = m16 * 4 + w;                      // col map: n = m16*4 + nt
#pragma unroll
    for (int k = 0; k < 4; ++k)
#pragma unroll
      for (int j = 0; j < 4; ++j) {
        const int c = k * 16 + q * 4 + j;
        wraw[k * 4 + j] = (c < CC) ? W[c * DD + nb] : 0.0f;
      }
  }
  float wmr[13];
  const int c0 = w * 13;
#pragma unroll
  for (int i = 0; i < 13; ++i) {
    const int c = c0 + i;
    wmr[i] = (c < CC) ? Wm[c * DD + L] : 0.0f;
  }
  const float gl = gamma[L], bl = beta[L];

  // ---- phase 1: x prefetch chunks 0..2 (39 VMEM in flight) ----
  float x0[4][4], x1[4][4], x2[4][4];
  int tm0, tm1, tm2, tm3;
  loadX(x, tmask, rowBase,      q, m16, L, x0, tm0);
  loadX(x, tmask, rowBase + 16, q, m16, L, x1, tm1);
  loadX(x, tmask, rowBase + 32, q, m16, L, x2, tm2);

  // ---- phase 2: consume preamble -> LDS table + red partials ----
  {
#pragma unroll
    for (int k = 0; k < 4; ++k) {
      int hl[4];
#pragma unroll
      for (int j = 0; j < 4; ++j) {
        const int c = k * 16 + q * 4 + j;
        const int smv = (c < CC) ? smB[c] : 1;
        const float we = smv ? 0.0f : wraw[k * 4 + j];
        const unsigned u = __float_as_uint(we);
        const unsigned h = u >> 16;
        const float hf = __uint_as_float(u & 0xFFFF0000u);
        const unsigned l = __float_as_uint(we - hf) >> 16;
        hl[j] = (int)(h | (l << 16));
      }
      __builtin_memcpy(&tabHL[k][w][L][0], hl, 16);  // lane-contiguous b128
    }
  }
  {
    float bs = 0.0f, f = 0.0f;
#pragma unroll
    for (int i = 0; i < 13; ++i) {
      const int c = c0 + i;
      const float sf = (c < CC) ? (float)smB[c] : 0.0f;
      bs = fmaf(sf, wmr[i], bs);
      f += wmr[i];
    }
    red[w * 2][L] = bs;
    red[w * 2 + 1][L] = f;
  }
  __syncthreads();
  float biasL, consL;
  {
    const float bs = (red[0][L] + red[2][L]) + (red[4][L] + red[6][L]);
    const float f  = (red[1][L] + red[3][L]) + (red[5][L] + red[7][L]);
    biasL = bs;
    const float s1 = allsum64(f);
    const float s2 = allsum64(f * f);
    const float mu = s1 * (1.0f / 64.0f);
    const float vr = fmaf(-mu, mu, s2 * (1.0f / 64.0f));
    const float rs = rsqrtf(vr + LN_EPS);
    consL = fmaf((f - mu) * rs, gl, bl);
  }
  float bias_[4], cons_[4], g_[4], b_[4];
#pragma unroll
  for (int nt = 0; nt < 4; ++nt) {
    const int src = m16 * 4 + nt;
    bias_[nt] = __shfl(biasL, src, 64);
    cons_[nt] = __shfl(consL, src, 64);
    g_[nt]    = __shfl(gl, src, 64);
    b_[nt]    = __shfl(bl, src, 64);
  }

  // ---- phase 3: pipelined chunk loop (all loads precede all stores) ----
  float* outW = out + (size_t)rowBase * DD;
  f32x4 acc[4];

  compMFMA(tabHL, x0, L, bias_, acc);                 // waits only ch0 loads
  loadX(x, tmask, rowBase + 48, q, m16, L, x0, tm3);  // ch3 into x0 (pre-store)
  lnStore(acc, tm0, q, m16, cons_, g_, b_, outW);

  compMFMA(tabHL, x1, L, bias_, acc);                 // ch1; ch2/ch3 in flight
  lnStore(acc, tm1, q, m16, cons_, g_, b_, outW + 16 * DD);

  compMFMA(tabHL, x2, L, bias_, acc);
  lnStore(acc, tm2, q, m16, cons_, g_, b_, outW + 32 * DD);

  compMFMA(tabHL, x0, L, bias_, acc);
  lnStore(acc, tm3, q, m16, cons_, g_, b_, outW + 48 * DD);
}

extern "C" void kernel_launch(void* const* d_in, const int* in_sizes, int n_in,
                              void* d_out, int out_size, void* d_ws, size_t ws_size,
                              hipStream_t stream) {
  const float* x     = (const float*)d_in[0];
  const float* W     = (const float*)d_in[1];
  const float* Wm    = (const float*)d_in[2];
  const float* gamma = (const float*)d_in[3];
  const float* beta  = (const float*)d_in[4];
  const int*   tmask = (const int*)d_in[5];
  const int*   smask = (const int*)d_in[6];
  float* out = (float*)d_out;

  ipmask_mfma12<<<dim3(1024), dim3(256), 0, stream>>>(
      x, W, Wm, gamma, beta, tmask, smask, out);
}